// Round 8
// baseline (1558.161 us; speedup 1.0000x reference)
//
#include <hip/hip_runtime.h>

#define BN 64
#define SN 128
#define TN 64
#define FN 100
#define G3 300
#define XW_BYTES 209715200L     /* B*S*T*F*4 */
#define NFLAGS 2048             /* 128 s-slices x 16 quads */

__device__ __forceinline__ float rl(float v, int l){
  return __int_as_float(__builtin_amdgcn_readlane(__float_as_int(v), l));
}
__device__ __forceinline__ float fast_exp(float x){        // e^x
  return __builtin_amdgcn_exp2f(x * 1.44269504088896341f);
}
__device__ __forceinline__ float fast_tanh(float x){
  float e = __builtin_amdgcn_exp2f(x * 2.88539008177792681f);
  return 1.0f - 2.0f * __builtin_amdgcn_rcpf(1.0f + e);
}
__device__ __forceinline__ float fast_sig(float x){
  return __builtin_amdgcn_rcpf(1.0f + __builtin_amdgcn_exp2f(-1.44269504088896341f * x));
}

// ---------------------------------------------------------------------------
// Standalone k_xw (round-0 v1, 445us known-good) — fallback path only.
// ---------------------------------------------------------------------------
__global__ __launch_bounds__(256, 3) void k_xw(
    const float* __restrict__ x, const float* __restrict__ W,
    const float* __restrict__ bias, float* __restrict__ xw)
{
  const long row = (long)blockIdx.x * 256 + threadIdx.x;
  const float4* xr4 = reinterpret_cast<const float4*>(x + row * FN);
  float acc[FN];
  #pragma unroll
  for (int j = 0; j < FN; j++) acc[j] = bias[j];
  #pragma unroll 1
  for (int fc = 0; fc < 25; fc++){
    float4 xv = xr4[fc];
    const float* Wr = W + fc * 4 * FN;
    #pragma unroll
    for (int j = 0; j < FN; j++) acc[j] = fmaf(xv.x, Wr[j],        acc[j]);
    #pragma unroll
    for (int j = 0; j < FN; j++) acc[j] = fmaf(xv.y, Wr[FN + j],   acc[j]);
    #pragma unroll
    for (int j = 0; j < FN; j++) acc[j] = fmaf(xv.z, Wr[2*FN + j], acc[j]);
    #pragma unroll
    for (int j = 0; j < FN; j++) acc[j] = fmaf(xv.w, Wr[3*FN + j], acc[j]);
  }
  float4* op = reinterpret_cast<float4*>(xw + row * FN);
  #pragma unroll
  for (int j = 0; j < 25; j++)
    op[j] = make_float4(acc[4*j], acc[4*j+1], acc[4*j+2], acc[4*j+3]);
}

// ---------------------------------------------------------------------------
// Fused producer-consumer kernel (round-7 design, hardened).
//  blocks 0..63   : scan (round-0 512-thr body; waits on tile flags if OVERLAP)
//  blocks 64..2111: xw producers, s-major. Block p: s=p>>4, batches [4(p&15),+4).
//    8 waves = 4 row-groups x 2 col-halves; each thread computes a 52-wide
//    column window -> acc[52]. W via wave-uniform s_load (v1 scheme).
//    f-order identical to v1 -> bit-identical xw.
//  Sync: producer: stores -> __syncthreads (drains vmcnt) -> tid0 agent-release
//  fence + device-scope flag. Scan: relaxed poll + agent-acquire fence before
//  issuing the tile's global_load_lds. Producers never wait -> no deadlock.
//  Hardening vs round 7: launch_bounds (512,2) (round-0 regalloc regime; the
//  (512,4)=128-VGPR cap risked loop spills), poll cap 50k x s_sleep(16)
//  (worst-case ~4s/run -> broken sync shows as FAILED, not container timeout).
// ---------------------------------------------------------------------------
template<int OVERLAP>
__global__ __launch_bounds__(512, 2) void k_fused(
    const float* __restrict__ x,  const float* __restrict__ W,
    const float* __restrict__ bias,
    const float* __restrict__ Wc, const float* __restrict__ u,
    const float* __restrict__ Wx, const float* __restrict__ Wh,
    const float* __restrict__ bg, float* __restrict__ xw,
    int* __restrict__ flags,      float* __restrict__ out)
{
  const int tid  = threadIdx.x;
  const int lane = tid & 63;
  const int wid  = tid >> 6;

  // ================= producer path =================
  if (blockIdx.x >= BN){
    const int p    = blockIdx.x - BN;          // 0..2047
    const int s    = p >> 4;
    const int q    = p & 15;
    const int half = wid & 1;                  // wave-uniform col-half
    const int rg   = wid >> 1;                 // row-group 0..3
    const int bb   = 4*q + rg;
    const long row = (long)bb*((long)SN*TN) + (long)s*TN + lane;
    const float4* xr4 = reinterpret_cast<const float4*>(x + row * FN);
    const int co = half ? 48 : 0;              // compute window [co, co+52)

    float acc[52];
    #pragma unroll
    for (int k = 0; k < 52; k++) acc[k] = bias[co + k];
    #pragma unroll 1
    for (int fc = 0; fc < 25; fc++){
      float4 xv = xr4[fc];
      const float* Wr = W + fc*4*FN + co;
      #pragma unroll
      for (int k = 0; k < 52; k++) acc[k] = fmaf(xv.x, Wr[k],        acc[k]);
      #pragma unroll
      for (int k = 0; k < 52; k++) acc[k] = fmaf(xv.y, Wr[FN + k],   acc[k]);
      #pragma unroll
      for (int k = 0; k < 52; k++) acc[k] = fmaf(xv.z, Wr[2*FN + k], acc[k]);
      #pragma unroll
      for (int k = 0; k < 52; k++) acc[k] = fmaf(xv.w, Wr[3*FN + k], acc[k]);
    }
    float4* op = reinterpret_cast<float4*>(xw + row * FN);
    if (!half){
      #pragma unroll
      for (int k = 0; k < 13; k++)   // cols 0..51
        op[k] = make_float4(acc[4*k], acc[4*k+1], acc[4*k+2], acc[4*k+3]);
    } else {
      #pragma unroll
      for (int k = 0; k < 12; k++)   // cols 52..99 = acc[4..51]
        op[13+k] = make_float4(acc[4+4*k], acc[5+4*k], acc[6+4*k], acc[7+4*k]);
    }
    __syncthreads();                           // all waves' stores drained (vmcnt0)
    if (tid == 0){
      __builtin_amdgcn_fence(__ATOMIC_RELEASE, "agent");
      __hip_atomic_store(&flags[p], 1, __ATOMIC_RELAXED, __HIP_MEMORY_SCOPE_AGENT);
    }
    return;
  }

  // ================= scan path (round-0 body + flag waits + bg regs) =======
  const int b = blockIdx.x;

  const int gth = tid & 127;
  const int fsl = tid >> 7;
  const int tB  = tid >> 3;
  const int fsB = tid & 7;
  const bool fCv = (tid & 127) < FN;
  const int fC  = fCv ? (tid & 127) : (FN - 1);
  const int tsC = tid >> 7;

  __shared__ __align__(16) float xwbuf[2][TN*FN + 16];
  __shared__ float part5[700][5];
  __shared__ float h_lds[128];
  __shared__ __align__(16) float c_lds[128];
  __shared__ float att_lds[128];
  __shared__ __align__(16) float ea_lds[64];
  __shared__ float dpart[8];

  float wr[25][5];
  float wcr[25];
  const bool hasC = (gth >= 28);
  const int  co   = hasC ? gth - 28 : 0;
  #pragma unroll
  for (int j = 0; j < 25; j++){
    const int f = fsl*25 + j;
    #pragma unroll
    for (int p = 0; p < 5; p++){
      const int o = gth + 128*p;
      wr[j][p] = (o < 600) ? ((o < 300) ? Wx[f*G3 + o] : Wh[f*G3 + (o-300)]) : 0.0f;
    }
    wcr[j] = hasC ? Wc[f*FN + co] : 0.0f;
  }
  float2 ur[7];
  #pragma unroll
  for (int i = 0; i < 7; i++){
    const int f = fsB*14 + 2*i;
    ur[i].x = (f   < FN) ? u[f]   : 0.0f;
    ur[i].y = (f+1 < FN) ? u[f+1] : 0.0f;
  }
  float bgz = 0.0f, bgr = 0.0f, bgh = 0.0f;
  if (tid < FN){ bgz = bg[tid]; bgr = bg[FN+tid]; bgh = bg[2*FN+tid]; }

  if (tid < 128){ h_lds[tid] = 0.0f; c_lds[tid] = 0.0f; att_lds[tid] = 0.0f; }
  if (tid < 16){ xwbuf[0][TN*FN + tid] = 0.0f; xwbuf[1][TN*FN + tid] = 0.0f; }
  __syncthreads();

  const long tileStride = (long)TN*FN;                 // 6400
  const float* xw_base = xw + (long)b*SN*tileStride;
  const float* x_base  = x  + (long)b*SN*tileStride;

  auto wait_tile = [&](int s_){
    if (OVERLAP){
      const int* fp = flags + s_*16 + (b>>2);
      int c = 0;
      while (!__hip_atomic_load(fp, __ATOMIC_RELAXED, __HIP_MEMORY_SCOPE_AGENT)){
        __builtin_amdgcn_s_sleep(16);
        if (++c > 50000) break;                // bounded: wrong-answer beats hang
      }
      __builtin_amdgcn_fence(__ATOMIC_ACQUIRE, "agent");
    }
  };

  auto issue_xw_dma = [&](int s, int bi){
    const char* g = (const char*)(xw_base + (long)s*tileStride);
    char* l = (char*)(&xwbuf[bi][0]);
    #pragma unroll
    for (int r = 0; r < 4; r++){
      const int chunk = (r*8 + wid) * 1024;
      if (chunk < 25600){
        __builtin_amdgcn_global_load_lds(
          (const __attribute__((address_space(1))) unsigned int*)(g + chunk + lane*16),
          (__attribute__((address_space(3))) unsigned int*)(l + chunk),
          16, 0, 0);
      }
    }
  };

#define ISSUE_X(sp, arr) do { \
    const float* gp_ = x_base + (long)(sp)*tileStride + (long)tsC*(16*FN) + fC; \
    _Pragma("unroll") \
    for (int k_ = 0; k_ < 16; k_++) arr[k_] = gp_[k_*FN]; \
  } while(0)

  float xcur[16], xnxt[16];
  wait_tile(0);
  issue_xw_dma(0, 0);
  ISSUE_X(0, xcur);

  for (int s = 0; s < SN; s++){
    // ---- phase A: c = h @ Wc ----
    float hp = h_lds[fsl*25 + (lane < 25 ? lane : 0)];
    float accC = 0.0f;
    #pragma unroll
    for (int j = 0; j < 25; j++) accC = fmaf(rl(hp, j), wcr[j], accC);
    if (hasC) part5[600 + co][fsl] = accC;
    __syncthreads();                                    // bar1

    if (tid < FN)
      c_lds[tid] = part5[600+tid][0] + part5[600+tid][1]
                 + part5[600+tid][2] + part5[600+tid][3];
    __syncthreads();                                    // bar2

    // ---- phase B ----
    {
      const float2* cp  = reinterpret_cast<const float2*>(&c_lds[fsB*14]);
      const float2* xp2 = reinterpret_cast<const float2*>(&xwbuf[s&1][tB*FN + fsB*14]);
      float accB = 0.0f;
      #pragma unroll
      for (int i = 0; i < 7; i++){
        float2 cc = cp[i];
        float2 xx = xp2[i];
        accB = fmaf(fast_tanh(xx.x + cc.x), ur[i].x, accB);
        accB = fmaf(fast_tanh(xx.y + cc.y), ur[i].y, accB);
      }
      accB += __shfl_xor(accB, 1);
      accB += __shfl_xor(accB, 2);
      accB += __shfl_xor(accB, 4);
      float ea = fast_exp(accB);
      if (fsB == 0) ea_lds[tB] = ea;
      float dsum = ea;
      dsum += __shfl_xor(dsum, 8);
      dsum += __shfl_xor(dsum, 16);
      dsum += __shfl_xor(dsum, 32);
      if (lane == 0) dpart[wid] = dsum;
    }
    __syncthreads();                                    // bar3

    // ---- phase C ----
    {
      const float4* eap = reinterpret_cast<const float4*>(&ea_lds[tsC*16]);
      float4 e0 = eap[0], e1 = eap[1], e2 = eap[2], e3 = eap[3];
      float a = 0.0f;
      a = fmaf(xcur[0],  e0.x, a); a = fmaf(xcur[1],  e0.y, a);
      a = fmaf(xcur[2],  e0.z, a); a = fmaf(xcur[3],  e0.w, a);
      a = fmaf(xcur[4],  e1.x, a); a = fmaf(xcur[5],  e1.y, a);
      a = fmaf(xcur[6],  e1.z, a); a = fmaf(xcur[7],  e1.w, a);
      a = fmaf(xcur[8],  e2.x, a); a = fmaf(xcur[9],  e2.y, a);
      a = fmaf(xcur[10], e2.z, a); a = fmaf(xcur[11], e2.w, a);
      a = fmaf(xcur[12], e3.x, a); a = fmaf(xcur[13], e3.y, a);
      a = fmaf(xcur[14], e3.z, a); a = fmaf(xcur[15], e3.w, a);
      if (fCv) part5[600 + fC][tsC] = a;
    }
    __syncthreads();                                    // bar4

    if (tid < FN){
      float den = dpart[0]+dpart[1]+dpart[2]+dpart[3]
                + dpart[4]+dpart[5]+dpart[6]+dpart[7] + 1e-7f;
      float sm = part5[600+tid][0]+part5[600+tid][1]
               + part5[600+tid][2]+part5[600+tid][3];
      att_lds[tid] = sm / den;
    }
    __syncthreads();                                    // bar5

    // ---- prefetch next tiles (flag-gated; phase D hides the latency) ----
    {
      const int sp = (s+1 < SN) ? s+1 : s;
      wait_tile(sp);
      issue_xw_dma(sp, (s+1)&1);
      ISSUE_X(sp, xnxt);
    }

    // ---- phase D ----
    {
      float attp = att_lds[fsl*25 + (lane < 25 ? lane : 0)];
      const bool p2x = (gth < 44);
      float a0=0.f, a1=0.f, a2=0.f, a3=0.f, a4=0.f;
      #pragma unroll
      for (int j = 0; j < 25; j++){
        float sa = rl(attp, j);
        float sh = rl(hp, j);
        float s2 = p2x ? sa : sh;
        a0 = fmaf(sa, wr[j][0], a0);
        a1 = fmaf(sa, wr[j][1], a1);
        a2 = fmaf(s2, wr[j][2], a2);
        a3 = fmaf(sh, wr[j][3], a3);
        a4 = fmaf(sh, wr[j][4], a4);
      }
      part5[gth      ][fsl] = a0;
      part5[gth + 128][fsl] = a1;
      part5[gth + 256][fsl] = a2;
      part5[gth + 384][fsl] = a3;
      if (gth < 88) part5[gth + 512][fsl] = a4;
    }
    __builtin_amdgcn_s_waitcnt(0x0F70);                 // vmcnt(0): DMA in LDS
    __syncthreads();                                    // bar6

    // ---- GRU update ----
    if (tid < FN){
      const int g = tid;
      float gxz = part5[g    ][0]+part5[g    ][1]+part5[g    ][2]+part5[g    ][3] + bgz;
      float gxr = part5[100+g][0]+part5[100+g][1]+part5[100+g][2]+part5[100+g][3] + bgr;
      float gxh = part5[200+g][0]+part5[200+g][1]+part5[200+g][2]+part5[200+g][3] + bgh;
      float ghz = part5[300+g][0]+part5[300+g][1]+part5[300+g][2]+part5[300+g][3];
      float ghr = part5[400+g][0]+part5[400+g][1]+part5[400+g][2]+part5[400+g][3];
      float ghh = part5[500+g][0]+part5[500+g][1]+part5[500+g][2]+part5[500+g][3];
      float z  = fast_sig(gxz + ghz);
      float r  = fast_sig(gxr + ghr);
      float ht = fast_tanh(gxh + r*ghh);
      float hn = (1.0f - z)*h_lds[g] + z*ht;
      h_lds[g] = hn;
      out[((long)b*SN + s)*FN + g] = hn;
    }
    __syncthreads();                                    // bar7
    #pragma unroll
    for (int k = 0; k < 16; k++) xcur[k] = xnxt[k];
  }
#undef ISSUE_X
}

extern "C" void kernel_launch(void* const* d_in, const int* in_sizes, int n_in,
                              void* d_out, int out_size, void* d_ws, size_t ws_size,
                              hipStream_t stream)
{
  const float* x  = (const float*)d_in[0];
  const float* W  = (const float*)d_in[1];
  const float* Wc = (const float*)d_in[2];
  const float* bb = (const float*)d_in[3];
  const float* u  = (const float*)d_in[4];
  const float* Wx = (const float*)d_in[5];
  const float* Wh = (const float*)d_in[6];
  const float* bg = (const float*)d_in[7];
  float* out = (float*)d_out;
  float* xwbuf = (float*)d_ws;                     // XW_BYTES
  int*   flags = (int*)((char*)d_ws + XW_BYTES);   // NFLAGS ints

  const bool overlap = ws_size >= (size_t)XW_BYTES + NFLAGS*sizeof(int);
  if (overlap){
    hipMemsetAsync(flags, 0, NFLAGS*sizeof(int), stream);
    k_fused<1><<<dim3(BN + 2048), dim3(512), 0, stream>>>(
        x, W, bb, Wc, u, Wx, Wh, bg, xwbuf, flags, out);
  } else {
    k_xw<<<dim3((BN*SN*TN) / 256), dim3(256), 0, stream>>>(x, W, bb, xwbuf);
    k_fused<0><<<dim3(BN), dim3(512), 0, stream>>>(
        x, W, bb, Wc, u, Wx, Wh, bg, xwbuf, nullptr, out);
  }
}

// Round 9
// 1150.510 us; speedup vs baseline: 1.3543x; 1.3543x over previous
//
#include <hip/hip_runtime.h>

#define BN 64
#define SN 128
#define TN 64
#define FN 100
#define G3 300
#define XW_BYTES 209715200L     /* B*S*T*F*4 */
#define NFLAGS 2048             /* 128 s-slices x 16 quads */

__device__ __forceinline__ float rl(float v, int l){
  return __int_as_float(__builtin_amdgcn_readlane(__float_as_int(v), l));
}
__device__ __forceinline__ float fast_exp(float x){        // e^x
  return __builtin_amdgcn_exp2f(x * 1.44269504088896341f);
}
__device__ __forceinline__ float fast_tanh(float x){
  float e = __builtin_amdgcn_exp2f(x * 2.88539008177792681f);
  return 1.0f - 2.0f * __builtin_amdgcn_rcpf(1.0f + e);
}
__device__ __forceinline__ float fast_sig(float x){
  return __builtin_amdgcn_rcpf(1.0f + __builtin_amdgcn_exp2f(-1.44269504088896341f * x));
}

// ---------------------------------------------------------------------------
// Standalone k_xw (round-0 v1, 445us known-good) — fallback path only.
// ---------------------------------------------------------------------------
__global__ __launch_bounds__(256, 3) void k_xw(
    const float* __restrict__ x, const float* __restrict__ W,
    const float* __restrict__ bias, float* __restrict__ xw)
{
  const long row = (long)blockIdx.x * 256 + threadIdx.x;
  const float4* xr4 = reinterpret_cast<const float4*>(x + row * FN);
  float acc[FN];
  #pragma unroll
  for (int j = 0; j < FN; j++) acc[j] = bias[j];
  #pragma unroll 1
  for (int fc = 0; fc < 25; fc++){
    float4 xv = xr4[fc];
    const float* Wr = W + fc * 4 * FN;
    #pragma unroll
    for (int j = 0; j < FN; j++) acc[j] = fmaf(xv.x, Wr[j],        acc[j]);
    #pragma unroll
    for (int j = 0; j < FN; j++) acc[j] = fmaf(xv.y, Wr[FN + j],   acc[j]);
    #pragma unroll
    for (int j = 0; j < FN; j++) acc[j] = fmaf(xv.z, Wr[2*FN + j], acc[j]);
    #pragma unroll
    for (int j = 0; j < FN; j++) acc[j] = fmaf(xv.w, Wr[3*FN + j], acc[j]);
  }
  float4* op = reinterpret_cast<float4*>(xw + row * FN);
  #pragma unroll
  for (int j = 0; j < 25; j++)
    op[j] = make_float4(acc[4*j], acc[4*j+1], acc[4*j+2], acc[4*j+3]);
}

// ---------------------------------------------------------------------------
// Fused producer-consumer kernel. Sync identical to round 8 (PASSED, bit-
// identical xw). Round-8 perf miss (1380us): producers ran ~2x their
// standalone speed; producer W was streamed via s_load (scalar cache = L2-
// backed), and the scan's 8192 per-step agent-acquire fences (buffer_inv,
// L2 scope) destroy that reuse. Round-9: producers stage W into LDS once
// (aliasing the scan path's xwbuf allocation -> LDS stays 66KB, 2 blocks/CU)
// and stream it via wave-uniform ds_read_b128 broadcast (v3 scheme, measured
// ~470us full-chip standalone, immune to L2 invalidation). f-accumulation
// order unchanged -> xw bit-identical.
// ---------------------------------------------------------------------------
template<int OVERLAP>
__global__ __launch_bounds__(512, 2) void k_fused(
    const float* __restrict__ x,  const float* __restrict__ W,
    const float* __restrict__ bias,
    const float* __restrict__ Wc, const float* __restrict__ u,
    const float* __restrict__ Wx, const float* __restrict__ Wh,
    const float* __restrict__ bg, float* __restrict__ xw,
    int* __restrict__ flags,      float* __restrict__ out)
{
  const int tid  = threadIdx.x;
  const int lane = tid & 63;
  const int wid  = tid >> 6;

  __shared__ __align__(16) float xwbuf[2][TN*FN + 16];   // scan dbuf / producer W
  __shared__ float part5[700][5];
  __shared__ float h_lds[128];
  __shared__ __align__(16) float c_lds[128];
  __shared__ float att_lds[128];
  __shared__ __align__(16) float ea_lds[64];
  __shared__ float dpart[8];

  // ================= producer path =================
  if (blockIdx.x >= BN){
    float* Wl = &xwbuf[0][0];                  // alias: 12832 floats >= 10000
    #pragma unroll 1
    for (int i = tid; i < FN*FN; i += 512) Wl[i] = W[i];
    __syncthreads();

    const int p    = blockIdx.x - BN;          // 0..2047
    const int s    = p >> 4;
    const int q    = p & 15;
    const int half = wid & 1;                  // wave-uniform col-half
    const int rg   = wid >> 1;                 // row-group 0..3
    const int bb   = 4*q + rg;
    const long row = (long)bb*((long)SN*TN) + (long)s*TN + lane;
    const float4* xr4 = reinterpret_cast<const float4*>(x + row * FN);
    const int cb4 = half ? 12 : 0;             // f4 col offset (cols 48 / 0)

    float acc[52];                             // window [4*cb4, 4*cb4+52)
    #pragma unroll
    for (int k = 0; k < 52; k++) acc[k] = bias[4*cb4 + k];

    const float4* wb = reinterpret_cast<const float4*>(Wl) + cb4;  // rows of 25 f4
    #pragma unroll 1
    for (int fc = 0; fc < 25; fc++){
      float4 xv = xr4[fc];
      #pragma unroll
      for (int j = 0; j < 4; j++){
        const float4* wr_ = wb + (4*fc + j) * 25;
        const float sx = (j==0) ? xv.x : (j==1) ? xv.y : (j==2) ? xv.z : xv.w;
        #pragma unroll
        for (int k = 0; k < 13; k++){
          float4 wv = wr_[k];
          acc[4*k+0] = fmaf(sx, wv.x, acc[4*k+0]);
          acc[4*k+1] = fmaf(sx, wv.y, acc[4*k+1]);
          acc[4*k+2] = fmaf(sx, wv.z, acc[4*k+2]);
          acc[4*k+3] = fmaf(sx, wv.w, acc[4*k+3]);
        }
      }
    }

    float4* op = reinterpret_cast<float4*>(xw + row * FN);
    if (!half){
      #pragma unroll
      for (int k = 0; k < 13; k++)   // cols 0..51
        op[k] = make_float4(acc[4*k], acc[4*k+1], acc[4*k+2], acc[4*k+3]);
    } else {
      #pragma unroll
      for (int k = 0; k < 12; k++)   // cols 52..99 = acc[4..51]
        op[13+k] = make_float4(acc[4+4*k], acc[5+4*k], acc[6+4*k], acc[7+4*k]);
    }
    __syncthreads();                           // all waves' stores drained
    if (tid == 0){
      __builtin_amdgcn_fence(__ATOMIC_RELEASE, "agent");
      __hip_atomic_store(&flags[p], 1, __ATOMIC_RELAXED, __HIP_MEMORY_SCOPE_AGENT);
    }
    return;
  }

  // ================= scan path (round-8, unchanged) =================
  const int b = blockIdx.x;

  const int gth = tid & 127;
  const int fsl = tid >> 7;
  const int tB  = tid >> 3;
  const int fsB = tid & 7;
  const bool fCv = (tid & 127) < FN;
  const int fC  = fCv ? (tid & 127) : (FN - 1);
  const int tsC = tid >> 7;

  float wr[25][5];
  float wcr[25];
  const bool hasC = (gth >= 28);
  const int  co   = hasC ? gth - 28 : 0;
  #pragma unroll
  for (int j = 0; j < 25; j++){
    const int f = fsl*25 + j;
    #pragma unroll
    for (int p = 0; p < 5; p++){
      const int o = gth + 128*p;
      wr[j][p] = (o < 600) ? ((o < 300) ? Wx[f*G3 + o] : Wh[f*G3 + (o-300)]) : 0.0f;
    }
    wcr[j] = hasC ? Wc[f*FN + co] : 0.0f;
  }
  float2 ur[7];
  #pragma unroll
  for (int i = 0; i < 7; i++){
    const int f = fsB*14 + 2*i;
    ur[i].x = (f   < FN) ? u[f]   : 0.0f;
    ur[i].y = (f+1 < FN) ? u[f+1] : 0.0f;
  }
  float bgz = 0.0f, bgr = 0.0f, bgh = 0.0f;
  if (tid < FN){ bgz = bg[tid]; bgr = bg[FN+tid]; bgh = bg[2*FN+tid]; }

  if (tid < 128){ h_lds[tid] = 0.0f; c_lds[tid] = 0.0f; att_lds[tid] = 0.0f; }
  if (tid < 16){ xwbuf[0][TN*FN + tid] = 0.0f; xwbuf[1][TN*FN + tid] = 0.0f; }
  __syncthreads();

  const long tileStride = (long)TN*FN;                 // 6400
  const float* xw_base = xw + (long)b*SN*tileStride;
  const float* x_base  = x  + (long)b*SN*tileStride;

  auto wait_tile = [&](int s_){
    if (OVERLAP){
      const int* fp = flags + s_*16 + (b>>2);
      int c = 0;
      while (!__hip_atomic_load(fp, __ATOMIC_RELAXED, __HIP_MEMORY_SCOPE_AGENT)){
        __builtin_amdgcn_s_sleep(16);
        if (++c > 50000) break;                // bounded: wrong-answer beats hang
      }
      __builtin_amdgcn_fence(__ATOMIC_ACQUIRE, "agent");
    }
  };

  auto issue_xw_dma = [&](int s, int bi){
    const char* g = (const char*)(xw_base + (long)s*tileStride);
    char* l = (char*)(&xwbuf[bi][0]);
    #pragma unroll
    for (int r = 0; r < 4; r++){
      const int chunk = (r*8 + wid) * 1024;
      if (chunk < 25600){
        __builtin_amdgcn_global_load_lds(
          (const __attribute__((address_space(1))) unsigned int*)(g + chunk + lane*16),
          (__attribute__((address_space(3))) unsigned int*)(l + chunk),
          16, 0, 0);
      }
    }
  };

#define ISSUE_X(sp, arr) do { \
    const float* gp_ = x_base + (long)(sp)*tileStride + (long)tsC*(16*FN) + fC; \
    _Pragma("unroll") \
    for (int k_ = 0; k_ < 16; k_++) arr[k_] = gp_[k_*FN]; \
  } while(0)

  float xcur[16], xnxt[16];
  wait_tile(0);
  issue_xw_dma(0, 0);
  ISSUE_X(0, xcur);

  for (int s = 0; s < SN; s++){
    // ---- phase A: c = h @ Wc ----
    float hp = h_lds[fsl*25 + (lane < 25 ? lane : 0)];
    float accC = 0.0f;
    #pragma unroll
    for (int j = 0; j < 25; j++) accC = fmaf(rl(hp, j), wcr[j], accC);
    if (hasC) part5[600 + co][fsl] = accC;
    __syncthreads();                                    // bar1

    if (tid < FN)
      c_lds[tid] = part5[600+tid][0] + part5[600+tid][1]
                 + part5[600+tid][2] + part5[600+tid][3];
    __syncthreads();                                    // bar2

    // ---- phase B ----
    {
      const float2* cp  = reinterpret_cast<const float2*>(&c_lds[fsB*14]);
      const float2* xp2 = reinterpret_cast<const float2*>(&xwbuf[s&1][tB*FN + fsB*14]);
      float accB = 0.0f;
      #pragma unroll
      for (int i = 0; i < 7; i++){
        float2 cc = cp[i];
        float2 xx = xp2[i];
        accB = fmaf(fast_tanh(xx.x + cc.x), ur[i].x, accB);
        accB = fmaf(fast_tanh(xx.y + cc.y), ur[i].y, accB);
      }
      accB += __shfl_xor(accB, 1);
      accB += __shfl_xor(accB, 2);
      accB += __shfl_xor(accB, 4);
      float ea = fast_exp(accB);
      if (fsB == 0) ea_lds[tB] = ea;
      float dsum = ea;
      dsum += __shfl_xor(dsum, 8);
      dsum += __shfl_xor(dsum, 16);
      dsum += __shfl_xor(dsum, 32);
      if (lane == 0) dpart[wid] = dsum;
    }
    __syncthreads();                                    // bar3

    // ---- phase C ----
    {
      const float4* eap = reinterpret_cast<const float4*>(&ea_lds[tsC*16]);
      float4 e0 = eap[0], e1 = eap[1], e2 = eap[2], e3 = eap[3];
      float a = 0.0f;
      a = fmaf(xcur[0],  e0.x, a); a = fmaf(xcur[1],  e0.y, a);
      a = fmaf(xcur[2],  e0.z, a); a = fmaf(xcur[3],  e0.w, a);
      a = fmaf(xcur[4],  e1.x, a); a = fmaf(xcur[5],  e1.y, a);
      a = fmaf(xcur[6],  e1.z, a); a = fmaf(xcur[7],  e1.w, a);
      a = fmaf(xcur[8],  e2.x, a); a = fmaf(xcur[9],  e2.y, a);
      a = fmaf(xcur[10], e2.z, a); a = fmaf(xcur[11], e2.w, a);
      a = fmaf(xcur[12], e3.x, a); a = fmaf(xcur[13], e3.y, a);
      a = fmaf(xcur[14], e3.z, a); a = fmaf(xcur[15], e3.w, a);
      if (fCv) part5[600 + fC][tsC] = a;
    }
    __syncthreads();                                    // bar4

    if (tid < FN){
      float den = dpart[0]+dpart[1]+dpart[2]+dpart[3]
                + dpart[4]+dpart[5]+dpart[6]+dpart[7] + 1e-7f;
      float sm = part5[600+tid][0]+part5[600+tid][1]
               + part5[600+tid][2]+part5[600+tid][3];
      att_lds[tid] = sm / den;
    }
    __syncthreads();                                    // bar5

    // ---- prefetch next tiles (flag-gated; phase D hides the latency) ----
    {
      const int sp = (s+1 < SN) ? s+1 : s;
      wait_tile(sp);
      issue_xw_dma(sp, (s+1)&1);
      ISSUE_X(sp, xnxt);
    }

    // ---- phase D ----
    {
      float attp = att_lds[fsl*25 + (lane < 25 ? lane : 0)];
      const bool p2x = (gth < 44);
      float a0=0.f, a1=0.f, a2=0.f, a3=0.f, a4=0.f;
      #pragma unroll
      for (int j = 0; j < 25; j++){
        float sa = rl(attp, j);
        float sh = rl(hp, j);
        float s2 = p2x ? sa : sh;
        a0 = fmaf(sa, wr[j][0], a0);
        a1 = fmaf(sa, wr[j][1], a1);
        a2 = fmaf(s2, wr[j][2], a2);
        a3 = fmaf(sh, wr[j][3], a3);
        a4 = fmaf(sh, wr[j][4], a4);
      }
      part5[gth      ][fsl] = a0;
      part5[gth + 128][fsl] = a1;
      part5[gth + 256][fsl] = a2;
      part5[gth + 384][fsl] = a3;
      if (gth < 88) part5[gth + 512][fsl] = a4;
    }
    __builtin_amdgcn_s_waitcnt(0x0F70);                 // vmcnt(0): DMA in LDS
    __syncthreads();                                    // bar6

    // ---- GRU update ----
    if (tid < FN){
      const int g = tid;
      float gxz = part5[g    ][0]+part5[g    ][1]+part5[g    ][2]+part5[g    ][3] + bgz;
      float gxr = part5[100+g][0]+part5[100+g][1]+part5[100+g][2]+part5[100+g][3] + bgr;
      float gxh = part5[200+g][0]+part5[200+g][1]+part5[200+g][2]+part5[200+g][3] + bgh;
      float ghz = part5[300+g][0]+part5[300+g][1]+part5[300+g][2]+part5[300+g][3];
      float ghr = part5[400+g][0]+part5[400+g][1]+part5[400+g][2]+part5[400+g][3];
      float ghh = part5[500+g][0]+part5[500+g][1]+part5[500+g][2]+part5[500+g][3];
      float z  = fast_sig(gxz + ghz);
      float r  = fast_sig(gxr + ghr);
      float ht = fast_tanh(gxh + r*ghh);
      float hn = (1.0f - z)*h_lds[g] + z*ht;
      h_lds[g] = hn;
      out[((long)b*SN + s)*FN + g] = hn;
    }
    __syncthreads();                                    // bar7
    #pragma unroll
    for (int k = 0; k < 16; k++) xcur[k] = xnxt[k];
  }
#undef ISSUE_X
}

extern "C" void kernel_launch(void* const* d_in, const int* in_sizes, int n_in,
                              void* d_out, int out_size, void* d_ws, size_t ws_size,
                              hipStream_t stream)
{
  const float* x  = (const float*)d_in[0];
  const float* W  = (const float*)d_in[1];
  const float* Wc = (const float*)d_in[2];
  const float* bb = (const float*)d_in[3];
  const float* u  = (const float*)d_in[4];
  const float* Wx = (const float*)d_in[5];
  const float* Wh = (const float*)d_in[6];
  const float* bg = (const float*)d_in[7];
  float* out = (float*)d_out;
  float* xwbuf = (float*)d_ws;                     // XW_BYTES
  int*   flags = (int*)((char*)d_ws + XW_BYTES);   // NFLAGS ints

  const bool overlap = ws_size >= (size_t)XW_BYTES + NFLAGS*sizeof(int);
  if (overlap){
    hipMemsetAsync(flags, 0, NFLAGS*sizeof(int), stream);
    k_fused<1><<<dim3(BN + 2048), dim3(512), 0, stream>>>(
        x, W, bb, Wc, u, Wx, Wh, bg, xwbuf, flags, out);
  } else {
    k_xw<<<dim3((BN*SN*TN) / 256), dim3(256), 0, stream>>>(x, W, bb, xwbuf);
    k_fused<0><<<dim3(BN), dim3(512), 0, stream>>>(
        x, W, bb, Wc, u, Wx, Wh, bg, xwbuf, nullptr, out);
  }
}